// Round 3
// baseline (1694.035 us; speedup 1.0000x reference)
//
#include <hip/hip_runtime.h>
#include <hip/hip_bf16.h>

#define DEV __device__ __forceinline__

typedef __attribute__((ext_vector_type(8))) short bf16x8;
typedef __attribute__((ext_vector_type(4))) float f32x4;
typedef __attribute__((ext_vector_type(8))) unsigned short u16x8;
typedef __attribute__((ext_vector_type(4))) unsigned short u16x4;
typedef unsigned int u32;

// ---------------- helpers ----------------
DEV float bf2f(unsigned short u) {
  union { u32 i; float f; } v; v.i = ((u32)u) << 16; return v.f;
}
DEV unsigned short f2bf(float f) {
  __hip_bfloat16 h = __float2bfloat16(f);
  return *reinterpret_cast<unsigned short*>(&h);
}

DEV void async_ld16(const void* g, void* lds_uniform, void* lds_lane) {
#if __has_builtin(__builtin_amdgcn_global_load_lds)
  __builtin_amdgcn_global_load_lds(
      (const __attribute__((address_space(1))) u32*)g,
      (__attribute__((address_space(3))) u32*)lds_uniform, 16, 0, 0);
  (void)lds_lane;
#else
  *(f32x4*)lds_lane = *(const f32x4*)g;
#endif
}

// ---------------- tiny weight-prep kernels ----------------
__global__ void f32_to_bf16_k(const float* __restrict__ in,
                              __hip_bfloat16* __restrict__ out, int n) {
  int i = blockIdx.x * 256 + threadIdx.x;
  if (i < n) out[i] = __float2bfloat16(in[i]);
}

// xproj_w (96,2048) f32 -> (128,2048) bf16, rows 96..127 zero
__global__ void pad_xproj_k(const float* __restrict__ in,
                            __hip_bfloat16* __restrict__ out) {
  int i = blockIdx.x * 256 + threadIdx.x;   // 128*2048 = 262144
  if (i < 128 * 2048) {
    int r = i >> 11;
    out[i] = (r < 96) ? __float2bfloat16(in[i]) : __float2bfloat16(0.f);
  }
}

// softmax over n-axis of the two weighted-avg weights (4,1024) and (5,1024)
__global__ void softmax_w_k(const float* __restrict__ wtm, const float* __restrict__ wcm,
                            float* __restrict__ smtm, float* __restrict__ smcm) {
  int s = blockIdx.x * 256 + threadIdx.x;
  if (s >= 1024) return;
  {
    float v[4], mx = -1e30f;
    #pragma unroll
    for (int j = 0; j < 4; j++) { v[j] = wtm[j * 1024 + s]; mx = fmaxf(mx, v[j]); }
    float sum = 0.f;
    #pragma unroll
    for (int j = 0; j < 4; j++) { v[j] = expf(v[j] - mx); sum += v[j]; }
    #pragma unroll
    for (int j = 0; j < 4; j++) smtm[j * 1024 + s] = v[j] / sum;
  }
  {
    float v[5], mx = -1e30f;
    #pragma unroll
    for (int j = 0; j < 5; j++) { v[j] = wcm[j * 1024 + s]; mx = fmaxf(mx, v[j]); }
    float sum = 0.f;
    #pragma unroll
    for (int j = 0; j < 5; j++) { v[j] = expf(v[j] - mx); sum += v[j]; }
    #pragma unroll
    for (int j = 0; j < 5; j++) smcm[j * 1024 + s] = v[j] / sum;
  }
}

// ---------------- prep stages (rms + weighted average) ----------------
DEV float block_sum256(float v, float* red) {
  #pragma unroll
  for (int o = 32; o > 0; o >>= 1) v += __shfl_xor(v, o, 64);
  const int lane = threadIdx.x & 63, wv = threadIdx.x >> 6;
  if (lane == 0) red[wv] = v;
  __syncthreads();
  return red[0] + red[1] + red[2] + red[3];
}

// block = (b,s). res1 = residual + hscm[:,1]; h = rms(res1)*nw;
// x = w0*hstm0 + w1*hstm1 + w2*hscm0 + w3*h  -> bf16
__global__ __launch_bounds__(256) void prep_tm_k(
    const float* __restrict__ residual, const float* __restrict__ hstm,
    const float* __restrict__ hscm, const float* __restrict__ nw,
    const float* __restrict__ sm, float* __restrict__ res1,
    __hip_bfloat16* __restrict__ xout) {
  __shared__ float red[4];
  const int b = blockIdx.x >> 10, s = blockIdx.x & 1023;
  const int t = threadIdx.x;
  const int base = ((b << 10) | s) << 10;
  const int h0 = ((((b << 1) | 0) << 10) | s) << 10;
  const int h1 = ((((b << 1) | 1) << 10) | s) << 10;
  float r[4]; float ss = 0.f;
  #pragma unroll
  for (int i = 0; i < 4; i++) {
    int dd = t + (i << 8);
    r[i] = residual[base + dd] + hscm[h1 + dd];
    ss += r[i] * r[i];
  }
  ss = block_sum256(ss, red);
  const float scale = rsqrtf(ss * (1.f / 1024.f) + 1e-5f);
  const float w0 = sm[s], w1 = sm[1024 + s], w2 = sm[2048 + s], w3 = sm[3072 + s];
  #pragma unroll
  for (int i = 0; i < 4; i++) {
    int dd = t + (i << 8);
    res1[base + dd] = r[i];
    float hn = r[i] * scale * nw[dd];
    float x = w0 * hstm[h0 + dd] + w1 * hstm[h1 + dd] + w2 * hscm[h0 + dd] + w3 * hn;
    xout[base + dd] = __float2bfloat16(x);
  }
}

// block = (b,s). res2 = res1 + out_tm (-> d_out, F32); h = rms(res2)*nw;
// x = w0*hstm0 + w1*hstm1 + w2*h + w3*hscm0 + w4*hscm1 -> f32 (xpre aliases res1!)
__global__ __launch_bounds__(256) void prep_cm_k(
    const float* res1, const float* __restrict__ out_tm,
    const float* __restrict__ hstm, const float* __restrict__ hscm,
    const float* __restrict__ nw, const float* __restrict__ sm,
    float* __restrict__ res2_out, float* xpre) {
  __shared__ float red[4];
  const int b = blockIdx.x >> 10, s = blockIdx.x & 1023;
  const int t = threadIdx.x;
  const int base = ((b << 10) | s) << 10;
  const int h0 = ((((b << 1) | 0) << 10) | s) << 10;
  const int h1 = ((((b << 1) | 1) << 10) | s) << 10;
  float r[4]; float ss = 0.f;
  #pragma unroll
  for (int i = 0; i < 4; i++) {
    int dd = t + (i << 8);
    r[i] = res1[base + dd] + out_tm[base + dd];
    ss += r[i] * r[i];
  }
  ss = block_sum256(ss, red);
  const float scale = rsqrtf(ss * (1.f / 1024.f) + 1e-5f);
  const float w0 = sm[s], w1 = sm[1024 + s], w2 = sm[2048 + s],
              w3 = sm[3072 + s], w4 = sm[4096 + s];
  #pragma unroll
  for (int i = 0; i < 4; i++) {
    int dd = t + (i << 8);
    res2_out[base + dd] = r[i];
    float hn = r[i] * scale * nw[dd];
    float x = w0 * hstm[h0 + dd] + w1 * hstm[h1 + dd] + w2 * hn +
              w3 * hscm[h0 + dd] + w4 * hscm[h1 + dd];
    xpre[base + dd] = x;
  }
}

// ---------------- bf16 MFMA GEMM: C[M,N] = A[M,K] * W[N,K]^T ----------------
// m97 structure: 128x128 tile, BK=32, 4 waves each 64x64, global_load_lds w=16.
// EPI: 0 = none, 1 = softplus(v + bias[col]) (for dt)
template <int EPI, bool OUTBF>
__global__ __launch_bounds__(256) void gemm_bt(
    const __hip_bfloat16* __restrict__ A, int lda,
    const __hip_bfloat16* __restrict__ W, int ldw,
    void* __restrict__ Cout, int ldc,
    const float* __restrict__ bias, int K) {
  __shared__ __hip_bfloat16 As[128 * 32];
  __shared__ __hip_bfloat16 Bs[128 * 32];
  const int t = threadIdx.x;
  const int wave = t >> 6, lane = t & 63;
  const int m0 = blockIdx.y * 128, n0 = blockIdx.x * 128;
  const int wm = (wave >> 1) * 64, wn = (wave & 1) * 64;
  const int lr = lane & 15, kq = lane >> 4;

  f32x4 acc[4][4] = {};

  for (int k0 = 0; k0 < K; k0 += 32) {
    __syncthreads();   // previous compute done reading LDS
    {
      const int s1 = t, s2 = t + 256;
      const int r1 = s1 >> 2, c1 = (s1 & 3) * 8;
      const int r2 = s2 >> 2, c2 = (s2 & 3) * 8;
      async_ld16(A + (long)(m0 + r1) * lda + k0 + c1, As + (s1 & ~63) * 8, As + s1 * 8);
      async_ld16(W + (long)(n0 + r1) * ldw + k0 + c1, Bs + (s1 & ~63) * 8, Bs + s1 * 8);
      async_ld16(A + (long)(m0 + r2) * lda + k0 + c2, As + (s2 & ~63) * 8, As + s2 * 8);
      async_ld16(W + (long)(n0 + r2) * ldw + k0 + c2, Bs + (s2 & ~63) * 8, Bs + s2 * 8);
    }
    __syncthreads();   // drains vmcnt -> staged tiles visible
    bf16x8 af[4], bfr[4];
    #pragma unroll
    for (int i = 0; i < 4; i++) {
      af[i]  = *(const bf16x8*)(As + (wm + i * 16 + lr) * 32 + kq * 8);
      bfr[i] = *(const bf16x8*)(Bs + (wn + i * 16 + lr) * 32 + kq * 8);
    }
    #pragma unroll
    for (int mt = 0; mt < 4; mt++)
      #pragma unroll
      for (int nt = 0; nt < 4; nt++)
        acc[mt][nt] = __builtin_amdgcn_mfma_f32_16x16x32_bf16(af[mt], bfr[nt], acc[mt][nt], 0, 0, 0);
  }

  // epilogue: C/D layout col=lane&15, row=(lane>>4)*4+reg  [m89-verified]
  #pragma unroll
  for (int nt = 0; nt < 4; nt++) {
    const int col = n0 + wn + nt * 16 + lr;
    const float bv = (EPI == 1) ? bias[col] : 0.0f;
    #pragma unroll
    for (int mt = 0; mt < 4; mt++) {
      #pragma unroll
      for (int r = 0; r < 4; r++) {
        const int row = m0 + wm + mt * 16 + kq * 4 + r;
        float v = acc[mt][nt][r];
        if (EPI == 1) { v += bv; v = (v > 20.f) ? v : log1pf(expf(v)); }
        if (OUTBF) ((__hip_bfloat16*)Cout)[(long)row * ldc + col] = __float2bfloat16(v);
        else       ((float*)Cout)[(long)row * ldc + col] = v;
      }
    }
  }
}

// ---------------- depthwise causal conv4 + bias + silu ----------------
// in: xz bf16 (B*1024, 4096), uses cols 0..2047; out: xh bf16 (B*1024, 2048)
__global__ __launch_bounds__(256) void conv_silu_k(
    const __hip_bfloat16* __restrict__ xz, const float* __restrict__ cw,
    const float* __restrict__ cb, __hip_bfloat16* __restrict__ xh) {
  const int idx = blockIdx.x * 256 + threadIdx.x;   // B*1024*256
  const int c = (idx & 255) << 3;
  const int l = (idx >> 8) & 1023;
  const int b = idx >> 18;
  f32x4 w[8];
  #pragma unroll
  for (int i = 0; i < 8; i++) w[i] = ((const f32x4*)cw)[c + i];
  float acc[8];
  #pragma unroll
  for (int i = 0; i < 8; i++) acc[i] = cb[c + i];
  #pragma unroll
  for (int j = 0; j < 4; j++) {
    int lp = l - 3 + j;
    if (lp >= 0) {
      u16x8 v = *(const u16x8*)(xz + (long)((b << 10) + lp) * 4096 + c);
      #pragma unroll
      for (int i = 0; i < 8; i++) acc[i] += bf2f(v[i]) * w[i][j];
    }
  }
  u16x8 o;
  #pragma unroll
  for (int i = 0; i < 8; i++) {
    float v = acc[i];
    float sg = 1.f / (1.f + exp2f(-1.44269504f * v));
    o[i] = f2bf(v * sg);
  }
  *(u16x8*)(xh + (long)((b << 10) + l) * 2048 + c) = o;
}

// ---------------- selective scan (fused D-residual + silu(z) gating) -------
// thread = (b, d, q): q in 0..3 owns states 4q..4q+3. 256 blocks x 256 thr.
// y is written into the x-half of xz (stride 4096) — dead after conv.
__global__ __launch_bounds__(256) void scan_k(
    const __hip_bfloat16* __restrict__ dtb,   // (B*1024, 2048) softplus'd dt
    const __hip_bfloat16* __restrict__ xh,    // (B*1024, 2048)
    const __hip_bfloat16* __restrict__ xdbl,  // (B*1024, 128): [64..79]=B, [80..95]=C
    __hip_bfloat16* __restrict__ xz,          // (B*1024, 4096): z = cols 2048.., y -> cols 0..2047
    const float* __restrict__ A_log,          // (2048,16)
    const float* __restrict__ Dp) {           // (2048,)
  const int blk = blockIdx.x;
  const int b = blk >> 5;
  const int d = ((blk & 31) << 6) + (threadIdx.x >> 2);
  const int q = threadIdx.x & 3;
  float a2[4];
  #pragma unroll
  for (int j = 0; j < 4; j++)
    a2[j] = -expf(A_log[d * 16 + q * 4 + j]) * 1.44269504f;  // A*log2(e)
  const float dpv = Dp[d];
  float h[4] = {0.f, 0.f, 0.f, 0.f};

  auto ld = [&](int tt, float& dtv, float& xv, float& zv, u16x4& Bv, u16x4& Cv) {
    const int rb = (b << 10) + tt;
    dtv = __bfloat162float(dtb[(long)rb * 2048 + d]);
    xv  = __bfloat162float(xh[(long)rb * 2048 + d]);
    zv  = __bfloat162float(xz[(long)rb * 4096 + 2048 + d]);
    Bv  = *(const u16x4*)(xdbl + (long)rb * 128 + 64 + q * 4);
    Cv  = *(const u16x4*)(xdbl + (long)rb * 128 + 80 + q * 4);
  };

  float dtv, xv, zv; u16x4 Bv, Cv;
  ld(0, dtv, xv, zv, Bv, Cv);
  for (int t = 0; t < 1024; t++) {
    float ndt, nx, nz; u16x4 nB, nC;
    const int tn = (t < 1023) ? t + 1 : 1023;
    ld(tn, ndt, nx, nz, nB, nC);       // prefetch next step
    const float dtx = dtv * xv;
    float p = 0.f;
    #pragma unroll
    for (int j = 0; j < 4; j++) {
      float e = exp2f(dtv * a2[j]);
      h[j] = e * h[j] + dtx * bf2f(Bv[j]);
      p += h[j] * bf2f(Cv[j]);
    }
    p += __shfl_xor(p, 1, 64);
    p += __shfl_xor(p, 2, 64);
    if (q == 0) {
      float yv = p + xv * dpv;
      float sg = 1.f / (1.f + exp2f(-1.44269504f * zv));
      xz[(long)((b << 10) + t) * 4096 + d] = __float2bfloat16(yv * zv * sg);
    }
    dtv = ndt; xv = nx; zv = nz; Bv = nB; Cv = nC;
  }
}

// ---------------- 64x64 tiled transpose (per-b), f32 in, T out -------------
DEV void cstore(float* p, float v) { *p = v; }
DEV void cstore(__hip_bfloat16* p, float v) { *p = __float2bfloat16(v); }

template <typename T>
__global__ __launch_bounds__(256) void transpose_k(
    const float* __restrict__ in, T* __restrict__ out, int R, int C) {
  __shared__ float tile[64][65];
  const int b = blockIdx.z;
  const int r0 = blockIdx.y << 6, c0 = blockIdx.x << 6;
  const int tx = threadIdx.x & 63, ty = threadIdx.x >> 6;
  const float* inb = in + (long)b * R * C;
  T* outb = out + (long)b * R * C;
  #pragma unroll
  for (int i = 0; i < 16; i++) {
    int r = (i << 2) + ty;
    tile[r][tx] = inb[(long)(r0 + r) * C + c0 + tx];
  }
  __syncthreads();
  #pragma unroll
  for (int i = 0; i < 16; i++) {
    int r = (i << 2) + ty;
    cstore(&outb[(long)(c0 + r) * R + r0 + tx], tile[tx][r]);
  }
}

// ---------------- launch ----------------
extern "C" void kernel_launch(void* const* d_in, const int* in_sizes, int n_in,
                              void* d_out, int out_size, void* d_ws, size_t ws_size,
                              hipStream_t stream) {
  const float* hstm      = (const float*)d_in[0];
  const float* hscm      = (const float*)d_in[1];
  const float* residual  = (const float*)d_in[2];
  const float* norm_tm_w = (const float*)d_in[3];
  const float* wavg_tm_w = (const float*)d_in[4];
  const float* norm_cm_w = (const float*)d_in[5];
  const float* wavg_cm_w = (const float*)d_in[6];
  const float* tm_in_w   = (const float*)d_in[7];
  const float* tm_conv_w = (const float*)d_in[8];
  const float* tm_conv_b = (const float*)d_in[9];
  const float* tm_xproj  = (const float*)d_in[10];
  const float* tm_dt_w   = (const float*)d_in[11];
  const float* tm_dt_b   = (const float*)d_in[12];
  const float* tm_A_log  = (const float*)d_in[13];
  const float* tm_D      = (const float*)d_in[14];
  const float* tm_out_w  = (const float*)d_in[15];
  const float* cm_in_w   = (const float*)d_in[16];
  const float* cm_conv_w = (const float*)d_in[17];
  const float* cm_conv_b = (const float*)d_in[18];
  const float* cm_xproj  = (const float*)d_in[19];
  const float* cm_dt_w   = (const float*)d_in[20];
  const float* cm_dt_b   = (const float*)d_in[21];
  const float* cm_A_log  = (const float*)d_in[22];
  const float* cm_D      = (const float*)d_in[23];
  const float* cm_out_w  = (const float*)d_in[24];

  // OUTPUT IS F32 (reference returns float32; round-2 evidence confirms).
  float* out_final = (float*)d_out;              // (B,S,D)
  float* res2_out  = (float*)d_out + 8388608;    // (B,S,D)

  char* W = (char*)d_ws;
  // compact layout (~191 MB total — proven within ws_size in round 2)
  const size_t OFF_XZ   = 0;                     // (8192,4096) bf16 64MB; x-half reused for y
  const size_t OFF_RES1 = 67108864;              // (8192,1024) f32  32MB (reused as x_cm_pre)
  const size_t OFF_XIN  = 100663296;             // (8192,1024) bf16 16MB
  const size_t OFF_XH   = 117440512;             // (8192,2048) bf16 32MB
  const size_t OFF_XDBL = 150994944;             // (8192,128)  bf16  2MB
  const size_t OFF_DT   = 153092096;             // (8192,2048) bf16 32MB — ALSO outf f32 (disjoint lifetime)
  const size_t OFF_SMTM = 186646528;             // 16KB
  const size_t OFF_SMCM = 186662912;             // 20KB
  const size_t OFF_WI   = 186683392;             // in_w bf16   8MB (tm then cm)
  const size_t OFF_WO   = 195072000;             // out_w bf16  4MB
  const size_t OFF_WX   = 199266304;             // xproj pad 512KB
  const size_t OFF_WD   = 199790592;             // dt_w bf16 256KB  -> end ~191MB

  __hip_bfloat16* xz   = (__hip_bfloat16*)(W + OFF_XZ);
  float*          res1 = (float*)(W + OFF_RES1);
  __hip_bfloat16* xin  = (__hip_bfloat16*)(W + OFF_XIN);
  __hip_bfloat16* xh   = (__hip_bfloat16*)(W + OFF_XH);
  __hip_bfloat16* xdbl = (__hip_bfloat16*)(W + OFF_XDBL);
  __hip_bfloat16* dtb  = (__hip_bfloat16*)(W + OFF_DT);
  float*          outf = (float*)(W + OFF_DT);   // alias: dt dead when outf written
  float*          smtm = (float*)(W + OFF_SMTM);
  float*          smcm = (float*)(W + OFF_SMCM);
  __hip_bfloat16* wi   = (__hip_bfloat16*)(W + OFF_WI);
  __hip_bfloat16* wo   = (__hip_bfloat16*)(W + OFF_WO);
  __hip_bfloat16* wx   = (__hip_bfloat16*)(W + OFF_WX);
  __hip_bfloat16* wd   = (__hip_bfloat16*)(W + OFF_WD);

  softmax_w_k<<<4, 256, 0, stream>>>(wavg_tm_w, wavg_cm_w, smtm, smcm);

  // ---- token mixer (convert tm weights into shared buffers first) ----
  f32_to_bf16_k<<<16384, 256, 0, stream>>>(tm_in_w,  wi, 4194304);
  f32_to_bf16_k<<<8192,  256, 0, stream>>>(tm_out_w, wo, 2097152);
  f32_to_bf16_k<<<512,   256, 0, stream>>>(tm_dt_w,  wd, 131072);
  pad_xproj_k  <<<1024,  256, 0, stream>>>(tm_xproj, wx);

  prep_tm_k<<<8192, 256, 0, stream>>>(residual, hstm, hscm, norm_tm_w, smtm, res1, xin);
  gemm_bt<0, true><<<dim3(32, 64), 256, 0, stream>>>(xin, 1024, wi, 1024, xz, 4096, nullptr, 1024);
  conv_silu_k<<<8192, 256, 0, stream>>>(xz, tm_conv_w, tm_conv_b, xh);
  gemm_bt<0, true><<<dim3(1, 64), 256, 0, stream>>>(xh, 2048, wx, 2048, xdbl, 128, nullptr, 2048);
  gemm_bt<1, true><<<dim3(16, 64), 256, 0, stream>>>(xdbl, 128, wd, 64, dtb, 2048, tm_dt_b, 64);
  scan_k<<<256, 256, 0, stream>>>(dtb, xh, xdbl, xz, tm_A_log, tm_D);
  gemm_bt<0, false><<<dim3(8, 64), 256, 0, stream>>>(xz, 4096, wo, 2048, outf, 1024, nullptr, 2048);

  // ---- channel-mixer prep (res2 -> d_out f32, x_cm_pre overwrites res1) ----
  prep_cm_k<<<8192, 256, 0, stream>>>(res1, outf, hstm, hscm, norm_cm_w, smcm, res2_out, res1);
  transpose_k<__hip_bfloat16><<<dim3(16, 16, 8), 256, 0, stream>>>(res1, xin, 1024, 1024);

  // ---- convert cm weights (tm GEMMs all done by stream order) ----
  f32_to_bf16_k<<<16384, 256, 0, stream>>>(cm_in_w,  wi, 4194304);
  f32_to_bf16_k<<<8192,  256, 0, stream>>>(cm_out_w, wo, 2097152);
  f32_to_bf16_k<<<512,   256, 0, stream>>>(cm_dt_w,  wd, 131072);
  pad_xproj_k  <<<1024,  256, 0, stream>>>(cm_xproj, wx);

  // ---- channel mixer (sequence axis = D) ----
  gemm_bt<0, true><<<dim3(32, 64), 256, 0, stream>>>(xin, 1024, wi, 1024, xz, 4096, nullptr, 1024);
  conv_silu_k<<<8192, 256, 0, stream>>>(xz, cm_conv_w, cm_conv_b, xh);
  gemm_bt<0, true><<<dim3(1, 64), 256, 0, stream>>>(xh, 2048, wx, 2048, xdbl, 128, nullptr, 2048);
  gemm_bt<1, true><<<dim3(16, 64), 256, 0, stream>>>(xdbl, 128, wd, 64, dtb, 2048, cm_dt_b, 64);
  scan_k<<<256, 256, 0, stream>>>(dtb, xh, xdbl, xz, cm_A_log, cm_D);
  gemm_bt<0, false><<<dim3(8, 64), 256, 0, stream>>>(xz, 4096, wo, 2048, outf, 1024, nullptr, 2048);
  transpose_k<float><<<dim3(16, 16, 8), 256, 0, stream>>>(outf, out_final, 1024, 1024);

  (void)in_sizes; (void)n_in; (void)out_size; (void)ws_size;
}

// Round 4
// 1490.142 us; speedup vs baseline: 1.1368x; 1.1368x over previous
//
#include <hip/hip_runtime.h>
#include <hip/hip_bf16.h>

#define DEV __device__ __forceinline__

typedef __attribute__((ext_vector_type(8))) short bf16x8;
typedef __attribute__((ext_vector_type(4))) float f32x4;
typedef __attribute__((ext_vector_type(8))) unsigned short u16x8;
typedef __attribute__((ext_vector_type(4))) unsigned short u16x4;
typedef unsigned int u32;

#define NCHUNK 8
#define CLEN 128   // 1024 / NCHUNK

// ---------------- helpers ----------------
DEV float bf2f(unsigned short u) {
  union { u32 i; float f; } v; v.i = ((u32)u) << 16; return v.f;
}
DEV unsigned short f2bf(float f) {
  __hip_bfloat16 h = __float2bfloat16(f);
  return *reinterpret_cast<unsigned short*>(&h);
}

DEV void async_ld16(const void* g, void* lds_uniform, void* lds_lane) {
#if __has_builtin(__builtin_amdgcn_global_load_lds)
  __builtin_amdgcn_global_load_lds(
      (const __attribute__((address_space(1))) u32*)g,
      (__attribute__((address_space(3))) u32*)lds_uniform, 16, 0, 0);
  (void)lds_lane;
#else
  *(f32x4*)lds_lane = *(const f32x4*)g;
#endif
}

// ---------------- tiny weight-prep kernels ----------------
__global__ void f32_to_bf16_k(const float* __restrict__ in,
                              __hip_bfloat16* __restrict__ out, int n) {
  int i = blockIdx.x * 256 + threadIdx.x;
  if (i < n) out[i] = __float2bfloat16(in[i]);
}

// xproj_w (96,2048) f32 -> (128,2048) bf16, rows 96..127 zero
__global__ void pad_xproj_k(const float* __restrict__ in,
                            __hip_bfloat16* __restrict__ out) {
  int i = blockIdx.x * 256 + threadIdx.x;   // 128*2048 = 262144
  if (i < 128 * 2048) {
    int r = i >> 11;
    out[i] = (r < 96) ? __float2bfloat16(in[i]) : __float2bfloat16(0.f);
  }
}

// softmax over n-axis of the two weighted-avg weights (4,1024) and (5,1024)
__global__ void softmax_w_k(const float* __restrict__ wtm, const float* __restrict__ wcm,
                            float* __restrict__ smtm, float* __restrict__ smcm) {
  int s = blockIdx.x * 256 + threadIdx.x;
  if (s >= 1024) return;
  {
    float v[4], mx = -1e30f;
    #pragma unroll
    for (int j = 0; j < 4; j++) { v[j] = wtm[j * 1024 + s]; mx = fmaxf(mx, v[j]); }
    float sum = 0.f;
    #pragma unroll
    for (int j = 0; j < 4; j++) { v[j] = expf(v[j] - mx); sum += v[j]; }
    #pragma unroll
    for (int j = 0; j < 4; j++) smtm[j * 1024 + s] = v[j] / sum;
  }
  {
    float v[5], mx = -1e30f;
    #pragma unroll
    for (int j = 0; j < 5; j++) { v[j] = wcm[j * 1024 + s]; mx = fmaxf(mx, v[j]); }
    float sum = 0.f;
    #pragma unroll
    for (int j = 0; j < 5; j++) { v[j] = expf(v[j] - mx); sum += v[j]; }
    #pragma unroll
    for (int j = 0; j < 5; j++) smcm[j * 1024 + s] = v[j] / sum;
  }
}

// ---------------- prep stages (rms + weighted average) ----------------
DEV float block_sum256(float v, float* red) {
  #pragma unroll
  for (int o = 32; o > 0; o >>= 1) v += __shfl_xor(v, o, 64);
  const int lane = threadIdx.x & 63, wv = threadIdx.x >> 6;
  if (lane == 0) red[wv] = v;
  __syncthreads();
  return red[0] + red[1] + red[2] + red[3];
}

__global__ __launch_bounds__(256) void prep_tm_k(
    const float* __restrict__ residual, const float* __restrict__ hstm,
    const float* __restrict__ hscm, const float* __restrict__ nw,
    const float* __restrict__ sm, float* __restrict__ res1,
    __hip_bfloat16* __restrict__ xout) {
  __shared__ float red[4];
  const int b = blockIdx.x >> 10, s = blockIdx.x & 1023;
  const int t = threadIdx.x;
  const int base = ((b << 10) | s) << 10;
  const int h0 = ((((b << 1) | 0) << 10) | s) << 10;
  const int h1 = ((((b << 1) | 1) << 10) | s) << 10;
  float r[4]; float ss = 0.f;
  #pragma unroll
  for (int i = 0; i < 4; i++) {
    int dd = t + (i << 8);
    r[i] = residual[base + dd] + hscm[h1 + dd];
    ss += r[i] * r[i];
  }
  ss = block_sum256(ss, red);
  const float scale = rsqrtf(ss * (1.f / 1024.f) + 1e-5f);
  const float w0 = sm[s], w1 = sm[1024 + s], w2 = sm[2048 + s], w3 = sm[3072 + s];
  #pragma unroll
  for (int i = 0; i < 4; i++) {
    int dd = t + (i << 8);
    res1[base + dd] = r[i];
    float hn = r[i] * scale * nw[dd];
    float x = w0 * hstm[h0 + dd] + w1 * hstm[h1 + dd] + w2 * hscm[h0 + dd] + w3 * hn;
    xout[base + dd] = __float2bfloat16(x);
  }
}

__global__ __launch_bounds__(256) void prep_cm_k(
    const float* res1, const float* __restrict__ out_tm,
    const float* __restrict__ hstm, const float* __restrict__ hscm,
    const float* __restrict__ nw, const float* __restrict__ sm,
    float* __restrict__ res2_out, float* xpre) {
  __shared__ float red[4];
  const int b = blockIdx.x >> 10, s = blockIdx.x & 1023;
  const int t = threadIdx.x;
  const int base = ((b << 10) | s) << 10;
  const int h0 = ((((b << 1) | 0) << 10) | s) << 10;
  const int h1 = ((((b << 1) | 1) << 10) | s) << 10;
  float r[4]; float ss = 0.f;
  #pragma unroll
  for (int i = 0; i < 4; i++) {
    int dd = t + (i << 8);
    r[i] = res1[base + dd] + out_tm[base + dd];
    ss += r[i] * r[i];
  }
  ss = block_sum256(ss, red);
  const float scale = rsqrtf(ss * (1.f / 1024.f) + 1e-5f);
  const float w0 = sm[s], w1 = sm[1024 + s], w2 = sm[2048 + s],
              w3 = sm[3072 + s], w4 = sm[4096 + s];
  #pragma unroll
  for (int i = 0; i < 4; i++) {
    int dd = t + (i << 8);
    res2_out[base + dd] = r[i];
    float hn = r[i] * scale * nw[dd];
    float x = w0 * hstm[h0 + dd] + w1 * hstm[h1 + dd] + w2 * hn +
              w3 * hscm[h0 + dd] + w4 * hscm[h1 + dd];
    xpre[base + dd] = x;
  }
}

// ---------------- bf16 MFMA GEMM: C[M,N] = A[M,K] * W[N,K]^T ----------------
template <int EPI, bool OUTBF>
__global__ __launch_bounds__(256) void gemm_bt(
    const __hip_bfloat16* __restrict__ A, int lda,
    const __hip_bfloat16* __restrict__ W, int ldw,
    void* __restrict__ Cout, int ldc,
    const float* __restrict__ bias, int K) {
  __shared__ __hip_bfloat16 As[128 * 32];
  __shared__ __hip_bfloat16 Bs[128 * 32];
  const int t = threadIdx.x;
  const int wave = t >> 6, lane = t & 63;
  const int m0 = blockIdx.y * 128, n0 = blockIdx.x * 128;
  const int wm = (wave >> 1) * 64, wn = (wave & 1) * 64;
  const int lr = lane & 15, kq = lane >> 4;

  f32x4 acc[4][4] = {};

  for (int k0 = 0; k0 < K; k0 += 32) {
    __syncthreads();
    {
      const int s1 = t, s2 = t + 256;
      const int r1 = s1 >> 2, c1 = (s1 & 3) * 8;
      const int r2 = s2 >> 2, c2 = (s2 & 3) * 8;
      async_ld16(A + (long)(m0 + r1) * lda + k0 + c1, As + (s1 & ~63) * 8, As + s1 * 8);
      async_ld16(W + (long)(n0 + r1) * ldw + k0 + c1, Bs + (s1 & ~63) * 8, Bs + s1 * 8);
      async_ld16(A + (long)(m0 + r2) * lda + k0 + c2, As + (s2 & ~63) * 8, As + s2 * 8);
      async_ld16(W + (long)(n0 + r2) * ldw + k0 + c2, Bs + (s2 & ~63) * 8, Bs + s2 * 8);
    }
    __syncthreads();
    bf16x8 af[4], bfr[4];
    #pragma unroll
    for (int i = 0; i < 4; i++) {
      af[i]  = *(const bf16x8*)(As + (wm + i * 16 + lr) * 32 + kq * 8);
      bfr[i] = *(const bf16x8*)(Bs + (wn + i * 16 + lr) * 32 + kq * 8);
    }
    #pragma unroll
    for (int mt = 0; mt < 4; mt++)
      #pragma unroll
      for (int nt = 0; nt < 4; nt++)
        acc[mt][nt] = __builtin_amdgcn_mfma_f32_16x16x32_bf16(af[mt], bfr[nt], acc[mt][nt], 0, 0, 0);
  }

  #pragma unroll
  for (int nt = 0; nt < 4; nt++) {
    const int col = n0 + wn + nt * 16 + lr;
    const float bv = (EPI == 1) ? bias[col] : 0.0f;
    #pragma unroll
    for (int mt = 0; mt < 4; mt++) {
      #pragma unroll
      for (int r = 0; r < 4; r++) {
        const int row = m0 + wm + mt * 16 + kq * 4 + r;
        float v = acc[mt][nt][r];
        if (EPI == 1) { v += bv; v = (v > 20.f) ? v : log1pf(expf(v)); }
        if (OUTBF) ((__hip_bfloat16*)Cout)[(long)row * ldc + col] = __float2bfloat16(v);
        else       ((float*)Cout)[(long)row * ldc + col] = v;
      }
    }
  }
}

// ---------------- depthwise causal conv4 + bias + silu ----------------
__global__ __launch_bounds__(256) void conv_silu_k(
    const __hip_bfloat16* __restrict__ xz, const float* __restrict__ cw,
    const float* __restrict__ cb, __hip_bfloat16* __restrict__ xh) {
  const int idx = blockIdx.x * 256 + threadIdx.x;
  const int c = (idx & 255) << 3;
  const int l = (idx >> 8) & 1023;
  const int b = idx >> 18;
  f32x4 w[8];
  #pragma unroll
  for (int i = 0; i < 8; i++) w[i] = ((const f32x4*)cw)[c + i];
  float acc[8];
  #pragma unroll
  for (int i = 0; i < 8; i++) acc[i] = cb[c + i];
  #pragma unroll
  for (int j = 0; j < 4; j++) {
    int lp = l - 3 + j;
    if (lp >= 0) {
      u16x8 v = *(const u16x8*)(xz + (long)((b << 10) + lp) * 4096 + c);
      #pragma unroll
      for (int i = 0; i < 8; i++) acc[i] += bf2f(v[i]) * w[i][j];
    }
  }
  u16x8 o;
  #pragma unroll
  for (int i = 0; i < 8; i++) {
    float v = acc[i];
    float sg = 1.f / (1.f + exp2f(-1.44269504f * v));
    o[i] = f2bf(v * sg);
  }
  *(u16x8*)(xh + (long)((b << 10) + l) * 2048 + c) = o;
}

// ---------------- chunked selective scan --------------------------------
// Pass 1: per (b, d, q, chunk) compute local decay product & local state.
// grid 2048 blocks: blk = ((b*32 + dg)*8 + c); thread = 64 d x 4 q.
__global__ __launch_bounds__(256) void scan_p1(
    const __hip_bfloat16* __restrict__ dtb,
    const __hip_bfloat16* __restrict__ xh,
    const __hip_bfloat16* __restrict__ xdbl,
    const float* __restrict__ A_log,
    float* __restrict__ AP, float* __restrict__ HH) {
  const int c  = blockIdx.x & 7;
  const int dg = (blockIdx.x >> 3) & 31;
  const int b  = blockIdx.x >> 8;
  const int d  = (dg << 6) + (threadIdx.x >> 2);
  const int q  = threadIdx.x & 3;
  float a2[4];
  #pragma unroll
  for (int j = 0; j < 4; j++)
    a2[j] = -expf(A_log[d * 16 + q * 4 + j]) * 1.44269504f;
  float ap[4] = {1.f, 1.f, 1.f, 1.f};
  float h[4]  = {0.f, 0.f, 0.f, 0.f};

  const int t0 = c * CLEN;
  auto ld = [&](int tt, float& dtv, float& xv, u16x4& Bv) {
    const int rb = (b << 10) + tt;
    dtv = __bfloat162float(dtb[(long)rb * 2048 + d]);
    xv  = __bfloat162float(xh[(long)rb * 2048 + d]);
    Bv  = *(const u16x4*)(xdbl + (long)rb * 128 + 64 + q * 4);
  };
  float dtv, xv; u16x4 Bv;
  ld(t0, dtv, xv, Bv);
  for (int t = t0; t < t0 + CLEN; t++) {
    float ndt, nx; u16x4 nB;
    ld(t < t0 + CLEN - 1 ? t + 1 : t, ndt, nx, nB);
    const float dtx = dtv * xv;
    #pragma unroll
    for (int j = 0; j < 4; j++) {
      float e = exp2f(dtv * a2[j]);
      ap[j] *= e;
      h[j] = e * h[j] + dtx * bf2f(Bv[j]);
    }
    dtv = ndt; xv = nx; Bv = nB;
  }
  const long ch = ((long)b << 11) + d;                 // b*2048+d
  const long base = ((long)c * 16384 + ch) * 16 + q * 4;
  #pragma unroll
  for (int j = 0; j < 4; j++) { AP[base + j] = ap[j]; HH[base + j] = h[j]; }
}

// Pass 2: sequential combine over chunks. thread = (ch, state); 262144 thr.
__global__ __launch_bounds__(256) void scan_comb(
    const float* __restrict__ AP, const float* __restrict__ HH,
    float* __restrict__ HI) {
  const int i = blockIdx.x * 256 + threadIdx.x;   // ch*16 + s
  float h = 0.f;
  HI[i] = 0.f;
  #pragma unroll
  for (int c = 1; c < NCHUNK; c++) {
    h = AP[(long)(c - 1) * 262144 + i] * h + HH[(long)(c - 1) * 262144 + i];
    HI[(long)c * 262144 + i] = h;
  }
}

// Pass 3: re-scan chunk seeded with HI, emit y (D-residual + silu(z) gate).
// y written into x-half of xz (dead after conv).
__global__ __launch_bounds__(256) void scan_p3(
    const __hip_bfloat16* __restrict__ dtb,
    const __hip_bfloat16* __restrict__ xh,
    const __hip_bfloat16* __restrict__ xdbl,
    __hip_bfloat16* __restrict__ xz,
    const float* __restrict__ A_log, const float* __restrict__ Dp,
    const float* __restrict__ HI) {
  const int c  = blockIdx.x & 7;
  const int dg = (blockIdx.x >> 3) & 31;
  const int b  = blockIdx.x >> 8;
  const int d  = (dg << 6) + (threadIdx.x >> 2);
  const int q  = threadIdx.x & 3;
  float a2[4];
  #pragma unroll
  for (int j = 0; j < 4; j++)
    a2[j] = -expf(A_log[d * 16 + q * 4 + j]) * 1.44269504f;
  const float dpv = Dp[d];
  const long ch = ((long)b << 11) + d;
  float h[4];
  #pragma unroll
  for (int j = 0; j < 4; j++)
    h[j] = HI[((long)c * 16384 + ch) * 16 + q * 4 + j];

  const int t0 = c * CLEN;
  auto ld = [&](int tt, float& dtv, float& xv, float& zv, u16x4& Bv, u16x4& Cv) {
    const int rb = (b << 10) + tt;
    dtv = __bfloat162float(dtb[(long)rb * 2048 + d]);
    xv  = __bfloat162float(xh[(long)rb * 2048 + d]);
    zv  = __bfloat162float(xz[(long)rb * 4096 + 2048 + d]);
    Bv  = *(const u16x4*)(xdbl + (long)rb * 128 + 64 + q * 4);
    Cv  = *(const u16x4*)(xdbl + (long)rb * 128 + 80 + q * 4);
  };
  float dtv, xv, zv; u16x4 Bv, Cv;
  ld(t0, dtv, xv, zv, Bv, Cv);
  for (int t = t0; t < t0 + CLEN; t++) {
    float ndt, nx, nz; u16x4 nB, nC;
    ld(t < t0 + CLEN - 1 ? t + 1 : t, ndt, nx, nz, nB, nC);
    const float dtx = dtv * xv;
    float p = 0.f;
    #pragma unroll
    for (int j = 0; j < 4; j++) {
      float e = exp2f(dtv * a2[j]);
      h[j] = e * h[j] + dtx * bf2f(Bv[j]);
      p += h[j] * bf2f(Cv[j]);
    }
    p += __shfl_xor(p, 1, 64);
    p += __shfl_xor(p, 2, 64);
    if (q == 0) {
      float yv = p + xv * dpv;
      float sg = 1.f / (1.f + exp2f(-1.44269504f * zv));
      xz[(long)((b << 10) + t) * 4096 + d] = __float2bfloat16(yv * zv * sg);
    }
    dtv = ndt; xv = nx; zv = nz; Bv = nB; Cv = nC;
  }
}

// ---------------- 64x64 tiled transpose (per-b), f32 in, T out -------------
DEV void cstore(float* p, float v) { *p = v; }
DEV void cstore(__hip_bfloat16* p, float v) { *p = __float2bfloat16(v); }

template <typename T>
__global__ __launch_bounds__(256) void transpose_k(
    const float* __restrict__ in, T* __restrict__ out, int R, int C) {
  __shared__ float tile[64][65];
  const int b = blockIdx.z;
  const int r0 = blockIdx.y << 6, c0 = blockIdx.x << 6;
  const int tx = threadIdx.x & 63, ty = threadIdx.x >> 6;
  const float* inb = in + (long)b * R * C;
  T* outb = out + (long)b * R * C;
  #pragma unroll
  for (int i = 0; i < 16; i++) {
    int r = (i << 2) + ty;
    tile[r][tx] = inb[(long)(r0 + r) * C + c0 + tx];
  }
  __syncthreads();
  #pragma unroll
  for (int i = 0; i < 16; i++) {
    int r = (i << 2) + ty;
    cstore(&outb[(long)(c0 + r) * R + r0 + tx], tile[tx][r]);
  }
}

// ---------------- launch ----------------
extern "C" void kernel_launch(void* const* d_in, const int* in_sizes, int n_in,
                              void* d_out, int out_size, void* d_ws, size_t ws_size,
                              hipStream_t stream) {
  const float* hstm      = (const float*)d_in[0];
  const float* hscm      = (const float*)d_in[1];
  const float* residual  = (const float*)d_in[2];
  const float* norm_tm_w = (const float*)d_in[3];
  const float* wavg_tm_w = (const float*)d_in[4];
  const float* norm_cm_w = (const float*)d_in[5];
  const float* wavg_cm_w = (const float*)d_in[6];
  const float* tm_in_w   = (const float*)d_in[7];
  const float* tm_conv_w = (const float*)d_in[8];
  const float* tm_conv_b = (const float*)d_in[9];
  const float* tm_xproj  = (const float*)d_in[10];
  const float* tm_dt_w   = (const float*)d_in[11];
  const float* tm_dt_b   = (const float*)d_in[12];
  const float* tm_A_log  = (const float*)d_in[13];
  const float* tm_D      = (const float*)d_in[14];
  const float* tm_out_w  = (const float*)d_in[15];
  const float* cm_in_w   = (const float*)d_in[16];
  const float* cm_conv_w = (const float*)d_in[17];
  const float* cm_conv_b = (const float*)d_in[18];
  const float* cm_xproj  = (const float*)d_in[19];
  const float* cm_dt_w   = (const float*)d_in[20];
  const float* cm_dt_b   = (const float*)d_in[21];
  const float* cm_A_log  = (const float*)d_in[22];
  const float* cm_D      = (const float*)d_in[23];
  const float* cm_out_w  = (const float*)d_in[24];

  float* out_final = (float*)d_out;              // (B,S,D) f32
  float* res2_out  = (float*)d_out + 8388608;    // (B,S,D) f32

  char* W = (char*)d_ws;
  const size_t OFF_XZ   = 0;                     // (8192,4096) bf16 64MB; x-half reused for y
  const size_t OFF_RES1 = 67108864;              // (8192,1024) f32  32MB (reused: x_cm_pre, then cm scan scratch)
  const size_t OFF_XIN  = 100663296;             // (8192,1024) bf16 16MB
  const size_t OFF_XH   = 117440512;             // (8192,2048) bf16 32MB
  const size_t OFF_XDBL = 150994944;             // (8192,128)  bf16  2MB
  const size_t OFF_DT   = 153092096;             // (8192,2048) bf16 32MB — ALSO outf f32 (disjoint lifetime)
  const size_t OFF_SMTM = 186646528;             // 16KB
  const size_t OFF_SMCM = 186662912;             // 20KB
  const size_t OFF_WI   = 186683392;             // in_w bf16   8MB (tm then cm)
  const size_t OFF_WO   = 195072000;             // out_w bf16  4MB
  const size_t OFF_WX   = 199266304;             // xproj pad 512KB
  const size_t OFF_WD   = 199790592;             // dt_w bf16 256KB  -> end ~191MB

  __hip_bfloat16* xz   = (__hip_bfloat16*)(W + OFF_XZ);
  float*          res1 = (float*)(W + OFF_RES1);
  __hip_bfloat16* xin  = (__hip_bfloat16*)(W + OFF_XIN);
  __hip_bfloat16* xh   = (__hip_bfloat16*)(W + OFF_XH);
  __hip_bfloat16* xdbl = (__hip_bfloat16*)(W + OFF_XDBL);
  __hip_bfloat16* dtb  = (__hip_bfloat16*)(W + OFF_DT);
  float*          outf = (float*)(W + OFF_DT);   // alias: dt dead when outf written
  float*          smtm = (float*)(W + OFF_SMTM);
  float*          smcm = (float*)(W + OFF_SMCM);
  __hip_bfloat16* wi   = (__hip_bfloat16*)(W + OFF_WI);
  __hip_bfloat16* wo   = (__hip_bfloat16*)(W + OFF_WO);
  __hip_bfloat16* wx   = (__hip_bfloat16*)(W + OFF_WX);
  __hip_bfloat16* wd   = (__hip_bfloat16*)(W + OFF_WD);

  // scan scratch: 3 x 8MB (AP, HH, HI), 2M floats each.
  // tm: lives in out_final region of d_out (overwritten by final transpose).
  float* tAP = (float*)d_out;
  float* tHH = tAP + 2097152;
  float* tHI = tHH + 2097152;
  // cm: lives in res1 region (dead after transpose consumed x_cm_pre).
  float* cAP = res1;
  float* cHH = cAP + 2097152;
  float* cHI = cHH + 2097152;

  softmax_w_k<<<4, 256, 0, stream>>>(wavg_tm_w, wavg_cm_w, smtm, smcm);

  // ---- token mixer ----
  f32_to_bf16_k<<<16384, 256, 0, stream>>>(tm_in_w,  wi, 4194304);
  f32_to_bf16_k<<<8192,  256, 0, stream>>>(tm_out_w, wo, 2097152);
  f32_to_bf16_k<<<512,   256, 0, stream>>>(tm_dt_w,  wd, 131072);
  pad_xproj_k  <<<1024,  256, 0, stream>>>(tm_xproj, wx);

  prep_tm_k<<<8192, 256, 0, stream>>>(residual, hstm, hscm, norm_tm_w, smtm, res1, xin);
  gemm_bt<0, true><<<dim3(32, 64), 256, 0, stream>>>(xin, 1024, wi, 1024, xz, 4096, nullptr, 1024);
  conv_silu_k<<<8192, 256, 0, stream>>>(xz, tm_conv_w, tm_conv_b, xh);
  gemm_bt<0, true><<<dim3(1, 64), 256, 0, stream>>>(xh, 2048, wx, 2048, xdbl, 128, nullptr, 2048);
  gemm_bt<1, true><<<dim3(16, 64), 256, 0, stream>>>(xdbl, 128, wd, 64, dtb, 2048, tm_dt_b, 64);
  scan_p1<<<2048, 256, 0, stream>>>(dtb, xh, xdbl, tm_A_log, tAP, tHH);
  scan_comb<<<1024, 256, 0, stream>>>(tAP, tHH, tHI);
  scan_p3<<<2048, 256, 0, stream>>>(dtb, xh, xdbl, xz, tm_A_log, tm_D, tHI);
  gemm_bt<0, false><<<dim3(8, 64), 256, 0, stream>>>(xz, 4096, wo, 2048, outf, 1024, nullptr, 2048);

  // ---- channel-mixer prep ----
  prep_cm_k<<<8192, 256, 0, stream>>>(res1, outf, hstm, hscm, norm_cm_w, smcm, res2_out, res1);
  transpose_k<__hip_bfloat16><<<dim3(16, 16, 8), 256, 0, stream>>>(res1, xin, 1024, 1024);

  f32_to_bf16_k<<<16384, 256, 0, stream>>>(cm_in_w,  wi, 4194304);
  f32_to_bf16_k<<<8192,  256, 0, stream>>>(cm_out_w, wo, 2097152);
  f32_to_bf16_k<<<512,   256, 0, stream>>>(cm_dt_w,  wd, 131072);
  pad_xproj_k  <<<1024,  256, 0, stream>>>(cm_xproj, wx);

  // ---- channel mixer ----
  gemm_bt<0, true><<<dim3(32, 64), 256, 0, stream>>>(xin, 1024, wi, 1024, xz, 4096, nullptr, 1024);
  conv_silu_k<<<8192, 256, 0, stream>>>(xz, cm_conv_w, cm_conv_b, xh);
  gemm_bt<0, true><<<dim3(1, 64), 256, 0, stream>>>(xh, 2048, wx, 2048, xdbl, 128, nullptr, 2048);
  gemm_bt<1, true><<<dim3(16, 64), 256, 0, stream>>>(xdbl, 128, wd, 64, dtb, 2048, cm_dt_b, 64);
  scan_p1<<<2048, 256, 0, stream>>>(dtb, xh, xdbl, cm_A_log, cAP, cHH);
  scan_comb<<<1024, 256, 0, stream>>>(cAP, cHH, cHI);
  scan_p3<<<2048, 256, 0, stream>>>(dtb, xh, xdbl, xz, cm_A_log, cm_D, cHI);
  gemm_bt<0, false><<<dim3(8, 64), 256, 0, stream>>>(xz, 4096, wo, 2048, outf, 1024, nullptr, 2048);
  transpose_k<float><<<dim3(16, 16, 8), 256, 0, stream>>>(outf, out_final, 1024, 1024);

  (void)in_sizes; (void)n_in; (void)out_size; (void)ws_size;
}